// Round 2
// baseline (17155.826 us; speedup 1.0000x reference)
//
#include <hip/hip_runtime.h>
#include <hip/hip_fp16.h>
#include <math.h>

#define NS   1024   // B*C sequences
#define TIN  4096
#define T1   2048
#define T2   1024
#define TW   64
#define K1   9
#define K2   7
#define NG   8
#define DD   128

__device__ __forceinline__ float gelu_f(float x) {
  return 0.5f * x * (1.0f + erff(x * 0.7071067811865476f));
}

// ---------------- Kernel A: conv1 stats per (n, group) --------------------
__global__ __launch_bounds__(256) void k_stats1(
    const float* __restrict__ x, const float* __restrict__ w1,
    float* __restrict__ stats1) {
  int n = blockIdx.x >> 3;
  int g = blockIdx.x & 7;
  __shared__ float xs[TIN + 8];
  __shared__ float ws[8][K1];
  __shared__ float rs[256], rq[256];
  const float* xrow = x + (size_t)n * TIN;
  for (int i = threadIdx.x; i < TIN + 8; i += 256) {
    int xi = i - 4;
    xs[i] = (xi >= 0 && xi < TIN) ? xrow[xi] : 0.f;
  }
  if (threadIdx.x < 8 * K1) {
    int ci = threadIdx.x / K1, k = threadIdx.x % K1;
    ws[ci][k] = w1[(g * 8 + ci) * K1 + k];
  }
  __syncthreads();
  int ci = threadIdx.x >> 5;
  int tb = threadIdx.x & 31;
  float w[K1];
#pragma unroll
  for (int k = 0; k < K1; k++) w[k] = ws[ci][k];
  float sum = 0.f, ssq = 0.f;
  for (int j = 0; j < 64; j++) {
    int t = tb + 32 * j;
    float acc = 0.f;
#pragma unroll
    for (int k = 0; k < K1; k++) acc += xs[2 * t + k] * w[k];
    sum += acc; ssq += acc * acc;
  }
  rs[threadIdx.x] = sum; rq[threadIdx.x] = ssq;
  __syncthreads();
  for (int s = 128; s > 0; s >>= 1) {
    if (threadIdx.x < s) { rs[threadIdx.x] += rs[threadIdx.x + s]; rq[threadIdx.x] += rq[threadIdx.x + s]; }
    __syncthreads();
  }
  if (threadIdx.x == 0) {
    float m = rs[0] * (1.f / 16384.f);
    float v = rq[0] * (1.f / 16384.f) - m * m;
    stats1[(n * NG + g) * 2 + 0] = m;
    stats1[(n * NG + g) * 2 + 1] = rsqrtf(v + 1e-5f);
  }
}

// ---------------- Kernel W: transpose conv2 weights to [k][co][ci] --------
__global__ __launch_bounds__(256) void k_w2t(const float* __restrict__ w2,
                                             float* __restrict__ w2t) {
  int idx = blockIdx.x * 256 + threadIdx.x;
  if (idx < TW * TW * K2) {
    int k = idx / (TW * TW);
    int r = idx % (TW * TW);
    int co = r >> 6, ci = r & 63;
    w2t[idx] = w2[(co * TW + ci) * K2 + k];
  }
}

// ---------------- Kernel B: conv2 (recompute conv1+GN1+gelu on the fly) ---
// block = (n, tile of 128 y2 timesteps). 256 thr = 8 cog x 32 tg.
// thread: 8 co x 4 t accumulators.
// MODE 0: stats only.  MODE 1: stats + fp16 y2 store.  MODE 2: apply GN2+gelu+mean.
template <int MODE>
__global__ __launch_bounds__(256, 3) void k_conv2(
    const float* __restrict__ x, const float* __restrict__ w1,
    const float* __restrict__ g1, const float* __restrict__ b1,
    const float* __restrict__ stats1, const float* __restrict__ w2t,
    const float* __restrict__ g2, const float* __restrict__ b2,
    __half* __restrict__ y2, float* __restrict__ stats2,
    float* __restrict__ hbar) {
  int n = blockIdx.x >> 3;
  int t0 = (blockIdx.x & 7) << 7;   // *128

  __shared__ float xs[532];                       // x[4*t0-10 .. 4*t0+518]
  __shared__ float w1s[TW][K1];
  __shared__ float sc[TW], bs[TW];
  __shared__ float h1s[261][17];                  // [t'][ci16] pad 17 (scalar reads)
  __shared__ __align__(16) float w2s[4][TW][20];  // [k-half][co][ci16] pad 20 (b128)

  const float* xrow = x + (size_t)n * TIN;
  for (int i = threadIdx.x; i < 529; i += 256) {
    int xi = 4 * t0 - 10 + i;
    xs[i] = (xi >= 0 && xi < TIN) ? xrow[xi] : 0.f;
  }
  for (int i = threadIdx.x; i < TW * K1; i += 256)
    w1s[i / K1][i % K1] = w1[i];
  if (threadIdx.x < TW) {
    int ci = threadIdx.x;
    int g = ci >> 3;
    float m = stats1[(n * NG + g) * 2 + 0];
    float is = stats1[(n * NG + g) * 2 + 1];
    float s = is * g1[ci];
    sc[ci] = s;
    bs[ci] = b1[ci] - m * s;
  }

  float acc[8][4];
#pragma unroll
  for (int a = 0; a < 8; a++)
#pragma unroll
    for (int j = 0; j < 4; j++) acc[a][j] = 0.f;

  const int cog = threadIdx.x >> 5;   // 8 groups of 8 co  (== GN2 group!)
  const int tg  = threadIdx.x & 31;   // 32 groups of 4 t (stride 32)

#define GEMM_HALF(KN, KB)                                                     \
  _Pragma("unroll") for (int c4 = 0; c4 < 16; c4 += 4) {                      \
    _Pragma("unroll") for (int kk = 0; kk < KN; ++kk) {                       \
      float4 wv[8];                                                           \
      float xv[4][4];                                                         \
      _Pragma("unroll") for (int a = 0; a < 8; ++a)                           \
        wv[a] = *(const float4*)&w2s[kk][cog * 8 + a][c4];                    \
      _Pragma("unroll") for (int j = 0; j < 4; ++j) {                         \
        int row = 2 * (tg + 32 * j) + (KB) + kk;                              \
        _Pragma("unroll") for (int e = 0; e < 4; ++e)                         \
          xv[j][e] = h1s[row][c4 + e];                                        \
      }                                                                       \
      _Pragma("unroll") for (int a = 0; a < 8; ++a)                           \
        _Pragma("unroll") for (int j = 0; j < 4; ++j)                         \
          acc[a][j] += wv[a].x * xv[j][0] + wv[a].y * xv[j][1] +              \
                       wv[a].z * xv[j][2] + wv[a].w * xv[j][3];               \
    }                                                                         \
  }

  for (int c = 0; c < 4; ++c) {
    const int ci0 = c << 4;
    __syncthreads();
    // recompute conv1 + GN1 + gelu into h1 chunk (16 ci x 261 t')
    for (int i = threadIdx.x; i < 261 * 16; i += 256) {
      int tl = i >> 4, cil = i & 15;
      int ci = ci0 + cil;
      int tp = 2 * t0 - 3 + tl;
      float v = 0.f;
      if (tp >= 0 && tp < T1) {
        float y = 0.f;
#pragma unroll
        for (int k = 0; k < K1; k++) y += xs[2 * tl + k] * w1s[ci][k];
        v = gelu_f(fmaf(y, sc[ci], bs[ci]));
      }
      h1s[tl][cil] = v;
    }
    // stage w2 k=0..3
    for (int i = threadIdx.x; i < 1024; i += 256) {
      int k = i >> 8, r = i & 255;
      int co = r >> 2, c4 = (r & 3) << 2;
      *(float4*)&w2s[k][co][c4] = *(const float4*)&w2t[(k * TW + co) * TW + ci0 + c4];
    }
    __syncthreads();
    GEMM_HALF(4, 0)
    __syncthreads();
    // stage w2 k=4..6
    for (int i = threadIdx.x; i < 768; i += 256) {
      int k = i >> 8, r = i & 255;
      int co = r >> 2, c4 = (r & 3) << 2;
      *(float4*)&w2s[k][co][c4] = *(const float4*)&w2t[((k + 4) * TW + co) * TW + ci0 + c4];
    }
    __syncthreads();
    GEMM_HALF(3, 4)
  }
#undef GEMM_HALF

  if constexpr (MODE == 0 || MODE == 1) {
    float sum = 0.f, ssq = 0.f;
#pragma unroll
    for (int a = 0; a < 8; a++) {
      int co = cog * 8 + a;
#pragma unroll
      for (int j = 0; j < 4; j++) {
        float v = acc[a][j];
        if (MODE == 1)
          y2[((size_t)n * TW + co) * T2 + t0 + tg + 32 * j] = __float2half(v);
        sum += v; ssq += v * v;
      }
    }
    // half-wave (32 lanes) share one cog == one GN2 group
#pragma unroll
    for (int off = 1; off < 32; off <<= 1) {
      sum += __shfl_xor(sum, off, 64);
      ssq += __shfl_xor(ssq, off, 64);
    }
    if ((threadIdx.x & 31) == 0) {
      atomicAdd(&stats2[(n * NG + cog) * 2 + 0], sum);
      atomicAdd(&stats2[(n * NG + cog) * 2 + 1], ssq);
    }
  } else {
    // MODE 2: read stats, normalize + gelu + partial time-mean
    float m  = stats2[(n * NG + cog) * 2 + 0] * (1.f / 8192.f);
    float e2 = stats2[(n * NG + cog) * 2 + 1] * (1.f / 8192.f);
    float istd = rsqrtf(e2 - m * m + 1e-5f);
    float s[8];
#pragma unroll
    for (int a = 0; a < 8; a++) {
      int co = cog * 8 + a;
      float sca = istd * g2[co];
      float sh = b2[co] - m * sca;
      float t = 0.f;
#pragma unroll
      for (int j = 0; j < 4; j++) t += gelu_f(fmaf(acc[a][j], sca, sh));
      s[a] = t;
    }
#pragma unroll
    for (int off = 1; off < 32; off <<= 1) {
#pragma unroll
      for (int a = 0; a < 8; a++) s[a] += __shfl_xor(s[a], off, 64);
    }
    if ((threadIdx.x & 31) == 0) {
#pragma unroll
      for (int a = 0; a < 8; a++)
        atomicAdd(&hbar[n * TW + cog * 8 + a], s[a]);
    }
  }
}

// ---------------- Kernel C: GN2 + gelu + time-sum (big path) --------------
__global__ __launch_bounds__(64) void k_gn2mean(
    const __half* __restrict__ y2, const float* __restrict__ stats2,
    const float* __restrict__ g2, const float* __restrict__ b2,
    float* __restrict__ hbar) {
  int n = blockIdx.x >> 6;
  int co = blockIdx.x & 63;
  int g = co >> 3;
  float m  = stats2[(n * NG + g) * 2 + 0] * (1.f / 8192.f);
  float e2 = stats2[(n * NG + g) * 2 + 1] * (1.f / 8192.f);
  float istd = rsqrtf(e2 - m * m + 1e-5f);
  float sca = istd * g2[co];
  float sh = b2[co] - m * sca;
  const __half2* row = (const __half2*)(y2 + ((size_t)n * TW + co) * T2);
  int lane = threadIdx.x;
  float s = 0.f;
#pragma unroll
  for (int i = 0; i < 8; i++) {
    float2 f = __half22float2(row[lane + 64 * i]);
    s += gelu_f(fmaf(f.x, sca, sh)) + gelu_f(fmaf(f.y, sca, sh));
  }
#pragma unroll
  for (int off = 1; off < 64; off <<= 1) s += __shfl_xor(s, off, 64);
  if (lane == 0) hbar[n * TW + co] = s;   // SUM over 1024 (k_head divides)
}

// ---------------- Kernel D: proj + GCN layers + LN + node mean ------------
__global__ __launch_bounds__(256) void k_head(
    const float* __restrict__ hbar,
    const float* __restrict__ pw, const float* __restrict__ pb,
    const float* __restrict__ A,
    const float* __restrict__ l1w, const float* __restrict__ l1g, const float* __restrict__ l1b,
    const float* __restrict__ l2w, const float* __restrict__ l2g, const float* __restrict__ l2b,
    const float* __restrict__ og, const float* __restrict__ ob,
    float* __restrict__ out) {
  int b = blockIdx.x;
  __shared__ float h4[4][TW];
  __shared__ float H[4][DD];
  __shared__ float Hm[4][DD];
  __shared__ float Xs[4][DD];
  __shared__ float At[16], Ah[16], dinv[4];
  {
    int i = threadIdx.x;
    int c = i >> 6, k = i & 63;
    h4[c][k] = hbar[(b * 4 + c) * TW + k] * (1.f / 1024.f);
  }
  if (threadIdx.x < 16)
    At[threadIdx.x] = A[threadIdx.x] + ((threadIdx.x % 5) == 0 ? 1.f : 0.f);
  __syncthreads();
  if (threadIdx.x < 4) {
    float dg = At[threadIdx.x * 4] + At[threadIdx.x * 4 + 1] +
               At[threadIdx.x * 4 + 2] + At[threadIdx.x * 4 + 3];
    dinv[threadIdx.x] = rsqrtf(dg + 1e-6f);
  }
  for (int idx = threadIdx.x; idx < 512; idx += 256) {
    int c = idx >> 7, d = idx & 127;
    float acc = pb[d];
    const float* wrow = pw + d * TW;
#pragma unroll 8
    for (int k = 0; k < TW; k++) acc += h4[c][k] * wrow[k];
    H[c][d] = acc;
  }
  __syncthreads();
  if (threadIdx.x < 16)
    Ah[threadIdx.x] = dinv[threadIdx.x >> 2] * At[threadIdx.x] * dinv[threadIdx.x & 3];
  __syncthreads();
  for (int L = 0; L < 2; L++) {
    const float* lw = L ? l2w : l1w;
    const float* lg = L ? l2g : l1g;
    const float* lb = L ? l2b : l1b;
    for (int idx = threadIdx.x; idx < 512; idx += 256) {
      int nn = idx >> 7, d = idx & 127;
      Hm[nn][d] = Ah[nn * 4 + 0] * H[0][d] + Ah[nn * 4 + 1] * H[1][d] +
                  Ah[nn * 4 + 2] * H[2][d] + Ah[nn * 4 + 3] * H[3][d];
    }
    __syncthreads();
    for (int idx = threadIdx.x; idx < 512; idx += 256) {
      int nn = idx >> 7, d = idx & 127;
      float acc = 0.f;
      const float* wrow = lw + d * DD;
#pragma unroll 8
      for (int k = 0; k < DD; k++) acc += Hm[nn][k] * wrow[k];
      Xs[nn][d] = acc;
    }
    __syncthreads();
    {
      int w = threadIdx.x >> 6, lane = threadIdx.x & 63;
      float v0 = Xs[w][lane], v1 = Xs[w][lane + 64];
      float s = v0 + v1, q = v0 * v0 + v1 * v1;
#pragma unroll
      for (int off = 1; off < 64; off <<= 1) {
        s += __shfl_xor(s, off, 64);
        q += __shfl_xor(q, off, 64);
      }
      float m = s * (1.f / 128.f);
      float istd = rsqrtf(q * (1.f / 128.f) - m * m + 1e-5f);
      H[w][lane]      = gelu_f((v0 - m) * istd * lg[lane] + lb[lane]);
      H[w][lane + 64] = gelu_f((v1 - m) * istd * lg[lane + 64] + lb[lane + 64]);
    }
    __syncthreads();
  }
  {
    int w = threadIdx.x >> 6, lane = threadIdx.x & 63;
    float v0 = H[w][lane], v1 = H[w][lane + 64];
    float s = v0 + v1, q = v0 * v0 + v1 * v1;
#pragma unroll
    for (int off = 1; off < 64; off <<= 1) {
      s += __shfl_xor(s, off, 64);
      q += __shfl_xor(q, off, 64);
    }
    float m = s * (1.f / 128.f);
    float istd = rsqrtf(q * (1.f / 128.f) - m * m + 1e-5f);
    Xs[w][lane]      = (v0 - m) * istd * og[lane] + ob[lane];
    Xs[w][lane + 64] = (v1 - m) * istd * og[lane + 64] + ob[lane + 64];
  }
  __syncthreads();
  if (threadIdx.x < DD) {
    int d = threadIdx.x;
    out[b * DD + d] = 0.25f * (Xs[0][d] + Xs[1][d] + Xs[2][d] + Xs[3][d]);
  }
}

extern "C" void kernel_launch(void* const* d_in, const int* in_sizes, int n_in,
                              void* d_out, int out_size, void* d_ws, size_t ws_size,
                              hipStream_t stream) {
  (void)in_sizes; (void)n_in; (void)out_size;
  const float* x       = (const float*)d_in[0];
  const float* conv1_w = (const float*)d_in[1];
  const float* gn1_g   = (const float*)d_in[2];
  const float* gn1_b   = (const float*)d_in[3];
  const float* conv2_w = (const float*)d_in[4];
  const float* gn2_g   = (const float*)d_in[5];
  const float* gn2_b   = (const float*)d_in[6];
  const float* proj_w  = (const float*)d_in[7];
  const float* proj_b  = (const float*)d_in[8];
  const float* A       = (const float*)d_in[9];
  const float* lin1_w  = (const float*)d_in[10];
  const float* ln1_g   = (const float*)d_in[11];
  const float* ln1_b   = (const float*)d_in[12];
  const float* lin2_w  = (const float*)d_in[13];
  const float* ln2_g   = (const float*)d_in[14];
  const float* ln2_b   = (const float*)d_in[15];
  const float* on_g    = (const float*)d_in[16];
  const float* on_b    = (const float*)d_in[17];
  float* out = (float*)d_out;

  // small buffers FIRST (total 126976 floats = 507904 B), big y2 (fp16) after
  float* wsf    = (float*)d_ws;
  float* stats1 = wsf;                 // 16384
  float* stats2 = stats1 + 16384;      // 16384
  float* hbar   = stats2 + 16384;      // 65536
  float* w2t    = hbar + 65536;        // 28672
  __half* y2h   = (__half*)(wsf + 126976);
  const size_t need_big = (size_t)126976 * 4 + (size_t)NS * TW * T2 * 2;
  const bool big = ws_size >= need_big;

  hipMemsetAsync(stats2, 0, 16384 * sizeof(float), stream);
  k_stats1<<<NS * NG, 256, 0, stream>>>(x, conv1_w, stats1);
  k_w2t<<<(TW * TW * K2 + 255) / 256, 256, 0, stream>>>(conv2_w, w2t);

  if (big) {
    k_conv2<1><<<NS * (T2 / 128), 256, 0, stream>>>(
        x, conv1_w, gn1_g, gn1_b, stats1, w2t, gn2_g, gn2_b, y2h, stats2, hbar);
    k_gn2mean<<<NS * TW, 64, 0, stream>>>(y2h, stats2, gn2_g, gn2_b, hbar);
  } else {
    hipMemsetAsync(hbar, 0, 65536 * sizeof(float), stream);
    k_conv2<0><<<NS * (T2 / 128), 256, 0, stream>>>(
        x, conv1_w, gn1_g, gn1_b, stats1, w2t, gn2_g, gn2_b, y2h, stats2, hbar);
    k_conv2<2><<<NS * (T2 / 128), 256, 0, stream>>>(
        x, conv1_w, gn1_g, gn1_b, stats1, w2t, gn2_g, gn2_b, y2h, stats2, hbar);
  }
  k_head<<<256, 256, 0, stream>>>(hbar, proj_w, proj_b, A,
                                  lin1_w, ln1_g, ln1_b,
                                  lin2_w, ln2_g, ln2_b,
                                  on_g, on_b, out);
}

// Round 3
// 521.423 us; speedup vs baseline: 32.9019x; 32.9019x over previous
//
#include <hip/hip_runtime.h>
#include <hip/hip_fp16.h>
#include <math.h>

#define NS   1024   // B*C sequences
#define TIN  4096
#define T1   2048
#define T2   1024
#define TW   64
#define NG   8
#define DD   128

typedef __attribute__((ext_vector_type(8))) short bf16x8;
typedef __attribute__((ext_vector_type(4))) float f32x4;

__device__ __forceinline__ unsigned int f2bf(float v) {
  unsigned int u = __float_as_uint(v);
  u = u + 0x7FFFu + ((u >> 16) & 1u);
  return u >> 16;
}

// cheap tanh-form gelu (|dev| < ~3e-3, below bf16 quantization of h1)
__device__ __forceinline__ float gelu_tanh(float x) {
  float u2 = 1.5957691216057308f * x * fmaf(0.044715f, x * x, 1.0f); // 2*sqrt(2/pi)*x*(1+c x^2)
  float e = __expf(u2);
  float r = __builtin_amdgcn_rcpf(e + 1.0f);
  return x - x * r;   // x * e/(e+1) == 0.5x(1+tanh)
}

// precise gelu via A&S 7.1.26 erf poly (|eps| <= 1.5e-7)
__device__ __forceinline__ float gelu_erf(float x) {
  float z = fabsf(x) * 0.7071067811865476f;
  float t = __builtin_amdgcn_rcpf(fmaf(0.3275911f, z, 1.0f));
  float p = fmaf(1.061405429f, t, -1.453152027f);
  p = fmaf(p, t, 1.421413741f);
  p = fmaf(p, t, -0.284496736f);
  p = fmaf(p, t, 0.254829592f);
  p = p * t;
  float e = __expf(-z * z);
  float erf = 1.0f - p * e;          // erf(|z|)
  float s = (x >= 0.f) ? erf : -erf;
  return 0.5f * x * (1.0f + s);
}

// ---------------- Kernel A: conv1 stats per (n, group), windowed ----------
__global__ __launch_bounds__(256) void k_stats1(
    const float* __restrict__ x, const float* __restrict__ w1,
    float* __restrict__ stats1) {
  int n = blockIdx.x >> 3;
  int g = blockIdx.x & 7;
  __shared__ float xs[4128];            // xs[i] = x[i-4]
  __shared__ float rs[256], rq[256];
  const float* xrow = x + (size_t)n * TIN;
  for (int i = threadIdx.x; i < 4128; i += 256) {
    int xi = i - 4;
    xs[i] = (xi >= 0 && xi < TIN) ? xrow[xi] : 0.f;
  }
  __syncthreads();
  int ci = threadIdx.x >> 5;            // 8 channels
  int ts = threadIdx.x & 31;            // 32 t-slices x 64 t
  float w[9];
#pragma unroll
  for (int k = 0; k < 9; k++) w[k] = w1[(g * 8 + ci) * 9 + k];
  int base = 2 * (ts * 64);             // y[t] = sum_k xs[2t+k]*w[k]
  float f[16];
  *(float4*)&f[0] = *(float4*)&xs[base];
  *(float4*)&f[4] = *(float4*)&xs[base + 4];
  float sum = 0.f, ssq = 0.f;
  for (int i = 0; i < 16; i++) {
    *(float4*)&f[8]  = *(float4*)&xs[base + 8 * i + 8];
    *(float4*)&f[12] = *(float4*)&xs[base + 8 * i + 12];
#pragma unroll
    for (int dd = 0; dd < 4; dd++) {
      float y = 0.f;
#pragma unroll
      for (int k = 0; k < 9; k++) y = fmaf(f[2 * dd + k], w[k], y);
      sum += y; ssq += y * y;
    }
#pragma unroll
    for (int j = 0; j < 8; j++) f[j] = f[j + 8];
  }
  rs[threadIdx.x] = sum; rq[threadIdx.x] = ssq;
  __syncthreads();
  for (int s = 128; s > 0; s >>= 1) {
    if (threadIdx.x < s) { rs[threadIdx.x] += rs[threadIdx.x + s]; rq[threadIdx.x] += rq[threadIdx.x + s]; }
    __syncthreads();
  }
  if (threadIdx.x == 0) {
    float m = rs[0] * (1.f / 16384.f);
    float v = rq[0] * (1.f / 16384.f) - m * m;
    stats1[(n * NG + g) * 2 + 0] = m;
    stats1[(n * NG + g) * 2 + 1] = rsqrtf(v + 1e-5f);
  }
}

// ---------------- Kernel W: conv2 weights -> bf16 [k][co][ci] -------------
__global__ __launch_bounds__(256) void k_w2b(const float* __restrict__ w2,
                                             unsigned short* __restrict__ w2tb) {
  int idx = blockIdx.x * 256 + threadIdx.x;
  if (idx < 7 * 64 * 64) {
    int kk = idx >> 12;
    int r = idx & 4095;
    int co = r >> 6, ci = r & 63;
    w2tb[idx] = (unsigned short)f2bf(w2[(co * 64 + ci) * 7 + kk]);
  }
}

// ---------------- Kernel B: conv2 as bf16 MFMA implicit GEMM --------------
// block = (n, 256-t2 tile). 256 thr = 4 waves; wave handles 64 t x 64 co.
// h1 (conv1+GN1+gelu) recomputed into LDS bf16; w2 b-frags read from global.
__global__ __launch_bounds__(256, 2) void k_conv2(
    const float* __restrict__ x, const float* __restrict__ w1,
    const float* __restrict__ g1, const float* __restrict__ b1,
    const float* __restrict__ stats1, const unsigned short* __restrict__ w2tb,
    __half* __restrict__ y2, float* __restrict__ stats2) {
  constexpr int TB = 256;
  constexpr int ROWS = 2 * TB + 5;      // 517
  constexpr int HS = 72;                // row stride in bf16 elems (144 B, 9 spans)
  __shared__ unsigned short h1s[ROWS * HS];   // 74448 B; reused as tr[256][72] fp16
  __shared__ float xs[1088];
  __shared__ float scs[TW], bss[TW];

  const int tid = threadIdx.x;
  const int n = blockIdx.x >> 2;
  const int t0 = (blockIdx.x & 3) * TB;

  const float* xrow = x + (size_t)n * TIN;
  for (int i = tid; i < 1088; i += 256) {
    int xi = 4 * t0 - 10 + i;
    xs[i] = (i < 1041 && xi >= 0 && xi < TIN) ? xrow[xi] : 0.f;
  }
  if (tid < TW) {
    int ci = tid, g = ci >> 3;
    float m = stats1[(n * NG + g) * 2 + 0];
    float is = stats1[(n * NG + g) * 2 + 1];
    float s = is * g1[ci];
    scs[ci] = s;
    bss[ci] = b1[ci] - m * s;
  }
  __syncthreads();

  // ---- recompute h1 chunk: thread = (ci pair, t-octant), windowed x ----
  {
    int ci2 = tid & 31;
    int tq = tid >> 5;                  // 0..7
    int ci0 = 2 * ci2;
    float wA[9], wB[9];
#pragma unroll
    for (int k = 0; k < 9; k++) {
      wA[k] = w1[ci0 * 9 + k];
      wB[k] = w1[(ci0 + 1) * 9 + k];
    }
    float sA = scs[ci0], bA = bss[ci0];
    float sB = scs[ci0 + 1], bB = bss[ci0 + 1];
    int tl0 = 66 * tq;
    int tlend = min(tl0 + 66, ROWS);
    int base = 2 * tl0;
    float f[16];
    *(float4*)&f[0] = *(float4*)&xs[base];
    *(float4*)&f[4] = *(float4*)&xs[base + 4];
    for (int i = 0; i < 17; i++) {
      *(float4*)&f[8]  = *(float4*)&xs[base + 8 * i + 8];
      *(float4*)&f[12] = *(float4*)&xs[base + 8 * i + 12];
#pragma unroll
      for (int dd = 0; dd < 4; dd++) {
        int tl = tl0 + 4 * i + dd;
        if (tl < tlend) {
          int tp = 2 * t0 - 3 + tl;
          float va = 0.f, vb = 0.f;
          if (tp >= 0 && tp < T1) {
            float ya = 0.f, yb = 0.f;
#pragma unroll
            for (int k = 0; k < 9; k++) {
              ya = fmaf(f[2 * dd + k], wA[k], ya);
              yb = fmaf(f[2 * dd + k], wB[k], yb);
            }
            va = gelu_tanh(fmaf(ya, sA, bA));
            vb = gelu_tanh(fmaf(yb, sB, bB));
          }
          unsigned int pk = f2bf(va) | (f2bf(vb) << 16);
          *(unsigned int*)&h1s[tl * HS + ci0] = pk;
        }
      }
#pragma unroll
      for (int j = 0; j < 8; j++) f[j] = f[j + 8];
    }
  }
  __syncthreads();

  // ---- MFMA main loop ----
  const int lane = tid & 63;
  const int wv = tid >> 6;              // wave: t-range wv*64
  const int m = lane & 15;
  const int q = lane >> 4;
  f32x4 acc[4][4];
#pragma unroll
  for (int mt = 0; mt < 4; mt++)
#pragma unroll
    for (int nt = 0; nt < 4; nt++) acc[mt][nt] = (f32x4){0.f, 0.f, 0.f, 0.f};

  for (int kk = 0; kk < 7; kk++) {
    bf16x8 afr[4][2], bfr[4][2];
#pragma unroll
    for (int mt = 0; mt < 4; mt++) {
      int tl = 2 * (wv * 64 + mt * 16 + m) + kk;
#pragma unroll
      for (int ks = 0; ks < 2; ks++)
        afr[mt][ks] = *(const bf16x8*)&h1s[tl * HS + 32 * ks + 8 * q];
    }
#pragma unroll
    for (int nt = 0; nt < 4; nt++) {
      int co = nt * 16 + m;
#pragma unroll
      for (int ks = 0; ks < 2; ks++)
        bfr[nt][ks] = *(const bf16x8*)&w2tb[(kk * 64 + co) * 64 + 32 * ks + 8 * q];
    }
#pragma unroll
    for (int ks = 0; ks < 2; ks++)
#pragma unroll
      for (int mt = 0; mt < 4; mt++)
#pragma unroll
        for (int nt = 0; nt < 4; nt++)
          acc[mt][nt] = __builtin_amdgcn_mfma_f32_16x16x32_bf16(
              afr[mt][ks], bfr[nt][ks], acc[mt][nt], 0, 0, 0);
  }

  // ---- epilogue: transpose via LDS + GN2 stats ----
  __syncthreads();                      // all h1s reads done; reuse as tr
  unsigned short* tr = h1s;             // [256 t][72] fp16 bits
  float sum[4] = {0.f, 0.f, 0.f, 0.f}, ssq[4] = {0.f, 0.f, 0.f, 0.f};
#pragma unroll
  for (int mt = 0; mt < 4; mt++)
#pragma unroll
    for (int nt = 0; nt < 4; nt++)
#pragma unroll
      for (int r = 0; r < 4; r++) {
        float v = acc[mt][nt][r];
        int tl = wv * 64 + mt * 16 + q * 4 + r;
        int co = nt * 16 + m;
        tr[tl * HS + co] = __half_as_ushort(__float2half(v));
        sum[nt] += v; ssq[nt] += v * v;
      }
  // reduce over co-within-group (xor 1,2,4) and t-lanes (xor 16,32)
#pragma unroll
  for (int nt = 0; nt < 4; nt++) {
    sum[nt] += __shfl_xor(sum[nt], 1, 64);  ssq[nt] += __shfl_xor(ssq[nt], 1, 64);
    sum[nt] += __shfl_xor(sum[nt], 2, 64);  ssq[nt] += __shfl_xor(ssq[nt], 2, 64);
    sum[nt] += __shfl_xor(sum[nt], 4, 64);  ssq[nt] += __shfl_xor(ssq[nt], 4, 64);
    sum[nt] += __shfl_xor(sum[nt], 16, 64); ssq[nt] += __shfl_xor(ssq[nt], 16, 64);
    sum[nt] += __shfl_xor(sum[nt], 32, 64); ssq[nt] += __shfl_xor(ssq[nt], 32, 64);
  }
  if ((lane & 0x37) == 0) {             // lanes 0 and 8
    int gb = (lane >> 3) & 1;
#pragma unroll
    for (int nt = 0; nt < 4; nt++) {
      int g = nt * 2 + gb;
      atomicAdd(&stats2[(n * NG + g) * 2 + 0], sum[nt]);
      atomicAdd(&stats2[(n * NG + g) * 2 + 1], ssq[nt]);
    }
  }
  __syncthreads();
  // coalesced y2 store, layout [n][t][co] fp16
  for (int idx = tid; idx < 2048; idx += 256) {
    int t = idx >> 3, c8 = (idx & 7) * 8;
    float4 v = *(float4*)&tr[t * HS + c8];
    *(float4*)&y2[((size_t)n * 1024 + t0 + t) * 64 + c8] = v;
  }
}

// ---------------- Kernel C: GN2 + gelu + time-sum -> hbar -----------------
__global__ __launch_bounds__(256) void k_gn2mean(
    const __half* __restrict__ y2, const float* __restrict__ stats2,
    const float* __restrict__ g2, const float* __restrict__ b2,
    float* __restrict__ hbar) {
  int n = blockIdx.x;
  int cop = threadIdx.x & 31;           // co pair
  int ts = threadIdx.x >> 5;            // 8 t-slices
  int co0 = cop * 2;
  int g = co0 >> 3;
  float m  = stats2[(n * NG + g) * 2 + 0] * (1.f / 8192.f);
  float e2 = stats2[(n * NG + g) * 2 + 1] * (1.f / 8192.f);
  float istd = rsqrtf(e2 - m * m + 1e-5f);
  float s0 = istd * g2[co0],     h0 = b2[co0] - m * s0;
  float s1 = istd * g2[co0 + 1], h1 = b2[co0 + 1] - m * s1;
  const __half2* base = (const __half2*)(y2 + (size_t)n * 1024 * 64);
  float a0 = 0.f, a1 = 0.f;
  for (int t = ts; t < 1024; t += 8) {
    float2 f = __half22float2(base[t * 32 + cop]);
    a0 += gelu_erf(fmaf(f.x, s0, h0));
    a1 += gelu_erf(fmaf(f.y, s1, h1));
  }
  __shared__ float red[8][64];
  red[ts][co0] = a0;
  red[ts][co0 + 1] = a1;
  __syncthreads();
  if (threadIdx.x < 64) {
    float s = 0.f;
#pragma unroll
    for (int j = 0; j < 8; j++) s += red[j][threadIdx.x];
    hbar[n * 64 + threadIdx.x] = s;     // SUM over 1024; k_head scales
  }
}

// ---------------- Kernel D: proj + GCN layers + LN + node mean ------------
__global__ __launch_bounds__(256) void k_head(
    const float* __restrict__ hbar,
    const float* __restrict__ pw, const float* __restrict__ pb,
    const float* __restrict__ A,
    const float* __restrict__ l1w, const float* __restrict__ l1g, const float* __restrict__ l1b,
    const float* __restrict__ l2w, const float* __restrict__ l2g, const float* __restrict__ l2b,
    const float* __restrict__ og, const float* __restrict__ ob,
    float* __restrict__ out) {
  int b = blockIdx.x;
  __shared__ float h4[4][TW];
  __shared__ float H[4][DD];
  __shared__ float Hm[4][DD];
  __shared__ float Xs[4][DD];
  __shared__ float At[16], Ah[16], dinv[4];
  {
    int i = threadIdx.x;
    int c = i >> 6, k = i & 63;
    h4[c][k] = hbar[(b * 4 + c) * TW + k] * (1.f / 1024.f);
  }
  if (threadIdx.x < 16)
    At[threadIdx.x] = A[threadIdx.x] + ((threadIdx.x % 5) == 0 ? 1.f : 0.f);
  __syncthreads();
  if (threadIdx.x < 4) {
    float dg = At[threadIdx.x * 4] + At[threadIdx.x * 4 + 1] +
               At[threadIdx.x * 4 + 2] + At[threadIdx.x * 4 + 3];
    dinv[threadIdx.x] = rsqrtf(dg + 1e-6f);
  }
  for (int idx = threadIdx.x; idx < 512; idx += 256) {
    int c = idx >> 7, d = idx & 127;
    float acc = pb[d];
    const float* wrow = pw + d * TW;
#pragma unroll 8
    for (int k = 0; k < TW; k++) acc += h4[c][k] * wrow[k];
    H[c][d] = acc;
  }
  __syncthreads();
  if (threadIdx.x < 16)
    Ah[threadIdx.x] = dinv[threadIdx.x >> 2] * At[threadIdx.x] * dinv[threadIdx.x & 3];
  __syncthreads();
  for (int L = 0; L < 2; L++) {
    const float* lw = L ? l2w : l1w;
    const float* lg = L ? l2g : l1g;
    const float* lb = L ? l2b : l1b;
    for (int idx = threadIdx.x; idx < 512; idx += 256) {
      int nn = idx >> 7, d = idx & 127;
      Hm[nn][d] = Ah[nn * 4 + 0] * H[0][d] + Ah[nn * 4 + 1] * H[1][d] +
                  Ah[nn * 4 + 2] * H[2][d] + Ah[nn * 4 + 3] * H[3][d];
    }
    __syncthreads();
    for (int idx = threadIdx.x; idx < 512; idx += 256) {
      int nn = idx >> 7, d = idx & 127;
      float acc = 0.f;
      const float* wrow = lw + d * DD;
#pragma unroll 8
      for (int k = 0; k < DD; k++) acc += Hm[nn][k] * wrow[k];
      Xs[nn][d] = acc;
    }
    __syncthreads();
    {
      int w = threadIdx.x >> 6, lane = threadIdx.x & 63;
      float v0 = Xs[w][lane], v1 = Xs[w][lane + 64];
      float s = v0 + v1, qq = v0 * v0 + v1 * v1;
#pragma unroll
      for (int off = 1; off < 64; off <<= 1) {
        s += __shfl_xor(s, off, 64);
        qq += __shfl_xor(qq, off, 64);
      }
      float m = s * (1.f / 128.f);
      float istd = rsqrtf(qq * (1.f / 128.f) - m * m + 1e-5f);
      H[w][lane]      = gelu_erf((v0 - m) * istd * lg[lane] + lb[lane]);
      H[w][lane + 64] = gelu_erf((v1 - m) * istd * lg[lane + 64] + lb[lane + 64]);
    }
    __syncthreads();
  }
  {
    int w = threadIdx.x >> 6, lane = threadIdx.x & 63;
    float v0 = H[w][lane], v1 = H[w][lane + 64];
    float s = v0 + v1, qq = v0 * v0 + v1 * v1;
#pragma unroll
    for (int off = 1; off < 64; off <<= 1) {
      s += __shfl_xor(s, off, 64);
      qq += __shfl_xor(qq, off, 64);
    }
    float m = s * (1.f / 128.f);
    float istd = rsqrtf(qq * (1.f / 128.f) - m * m + 1e-5f);
    Xs[w][lane]      = (v0 - m) * istd * og[lane] + ob[lane];
    Xs[w][lane + 64] = (v1 - m) * istd * og[lane + 64] + ob[lane + 64];
  }
  __syncthreads();
  if (threadIdx.x < DD) {
    int d = threadIdx.x;
    out[b * DD + d] = 0.25f * (Xs[0][d] + Xs[1][d] + Xs[2][d] + Xs[3][d]);
  }
}

extern "C" void kernel_launch(void* const* d_in, const int* in_sizes, int n_in,
                              void* d_out, int out_size, void* d_ws, size_t ws_size,
                              hipStream_t stream) {
  (void)in_sizes; (void)n_in; (void)out_size; (void)ws_size;
  const float* x       = (const float*)d_in[0];
  const float* conv1_w = (const float*)d_in[1];
  const float* gn1_g   = (const float*)d_in[2];
  const float* gn1_b   = (const float*)d_in[3];
  const float* conv2_w = (const float*)d_in[4];
  const float* gn2_g   = (const float*)d_in[5];
  const float* gn2_b   = (const float*)d_in[6];
  const float* proj_w  = (const float*)d_in[7];
  const float* proj_b  = (const float*)d_in[8];
  const float* A       = (const float*)d_in[9];
  const float* lin1_w  = (const float*)d_in[10];
  const float* ln1_g   = (const float*)d_in[11];
  const float* ln1_b   = (const float*)d_in[12];
  const float* lin2_w  = (const float*)d_in[13];
  const float* ln2_g   = (const float*)d_in[14];
  const float* ln2_b   = (const float*)d_in[15];
  const float* on_g    = (const float*)d_in[16];
  const float* on_b    = (const float*)d_in[17];
  float* out = (float*)d_out;

  float* wsf = (float*)d_ws;
  float* stats1 = wsf;                               // 16384 f
  float* stats2 = stats1 + 16384;                    // 16384 f
  float* hbar   = stats2 + 16384;                    // 65536 f
  unsigned short* w2tb = (unsigned short*)(wsf + 98304);   // 28672 us
  __half* y2h = (__half*)(wsf + 112640);             // 67108864 halfs

  hipMemsetAsync(stats2, 0, 16384 * sizeof(float), stream);
  k_stats1<<<NS * NG, 256, 0, stream>>>(x, conv1_w, stats1);
  k_w2b<<<112, 256, 0, stream>>>(conv2_w, w2tb);
  k_conv2<<<NS * 4, 256, 0, stream>>>(x, conv1_w, gn1_g, gn1_b,
                                      stats1, w2tb, y2h, stats2);
  k_gn2mean<<<NS, 256, 0, stream>>>(y2h, stats2, gn2_g, gn2_b, hbar);
  k_head<<<256, 256, 0, stream>>>(hbar, proj_w, proj_b, A,
                                  lin1_w, ln1_g, ln1_b,
                                  lin2_w, ln2_g, ln2_b,
                                  on_g, on_b, out);
}

// Round 4
// 460.976 us; speedup vs baseline: 37.2163x; 1.1311x over previous
//
#include <hip/hip_runtime.h>
#include <hip/hip_fp16.h>
#include <math.h>

#define NS   1024
#define TIN  4096
#define T1   2048
#define T2   1024
#define TW   64
#define NG   8
#define DD   128

typedef __attribute__((ext_vector_type(8))) short    bf16x8;
typedef __attribute__((ext_vector_type(8))) _Float16 f16x8;
typedef __attribute__((ext_vector_type(4))) float    f32x4;

__device__ __forceinline__ unsigned f2bf(float v) {
  unsigned u = __float_as_uint(v);
  u = u + 0x7FFFu + ((u >> 16) & 1u);
  return u >> 16;
}

// tanh-form gelu, exp folded to exp2 (|dev from exact| ~3e-4)
__device__ __forceinline__ float gelu_fast(float x) {
  float t = x * x;
  float p = fmaf(0.044715f, t, 1.0f);
  float u = 2.3022038f * x * p;              // 2*sqrt(2/pi)*log2(e)
  float e = exp2f(u);
  float r = __builtin_amdgcn_rcpf(e + 1.0f);
  return fmaf(-x, r, x);                      // x * e/(e+1)
}

// ---------------- Kernel A: conv1 stats per n via 9x9 Gram matrix ---------
// sum_t y = w.S ; sum_t y^2 = w^T C w, C/S shared across all 64 channels.
__global__ __launch_bounds__(64) void k_stats1(
    const float* __restrict__ x, const float* __restrict__ w1,
    float* __restrict__ stats1) {
  int n = blockIdx.x;
  __shared__ float xw[4112];                  // xw[i] = x[i-4], zero-padded
  const float* xr = x + (size_t)n * TIN;
  for (int i = threadIdx.x; i < 4112; i += 64) {
    int xi = i - 4;
    xw[i] = (xi >= 0 && xi < TIN) ? xr[xi] : 0.f;
  }
  __syncthreads();
  float C[45], S[9];
#pragma unroll
  for (int c = 0; c < 45; c++) C[c] = 0.f;
#pragma unroll
  for (int i = 0; i < 9; i++) S[i] = 0.f;
  int l = threadIdx.x;
  for (int j = 0; j < 32; j++) {
    int t = l + 64 * j;
    float w[9];
#pragma unroll
    for (int i = 0; i < 9; i++) w[i] = xw[2 * t + i];
#pragma unroll
    for (int i = 0; i < 9; i++) S[i] += w[i];
    int c = 0;
#pragma unroll
    for (int i = 0; i < 9; i++)
#pragma unroll
      for (int jj = i; jj < 9; jj++) { C[c] = fmaf(w[i], w[jj], C[c]); c++; }
  }
#pragma unroll
  for (int off = 1; off < 64; off <<= 1) {
#pragma unroll
    for (int i = 0; i < 9; i++) S[i] += __shfl_xor(S[i], off, 64);
#pragma unroll
    for (int c = 0; c < 45; c++) C[c] += __shfl_xor(C[c], off, 64);
  }
  // per-channel: lane = ci
  float wv[9];
#pragma unroll
  for (int i = 0; i < 9; i++) wv[i] = w1[l * 9 + i];
  float sm = 0.f, sq = 0.f;
  {
    int c = 0;
#pragma unroll
    for (int i = 0; i < 9; i++) {
      sm = fmaf(wv[i], S[i], sm);
#pragma unroll
      for (int jj = i; jj < 9; jj++) {
        float f = (jj == i) ? wv[i] * wv[jj] : 2.f * wv[i] * wv[jj];
        sq = fmaf(f, C[c], sq); c++;
      }
    }
  }
#pragma unroll
  for (int off = 1; off < 8; off <<= 1) {
    sm += __shfl_xor(sm, off, 64);
    sq += __shfl_xor(sq, off, 64);
  }
  if ((l & 7) == 0) {
    float m = sm * (1.f / 16384.f);
    float v = sq * (1.f / 16384.f) - m * m;
    stats1[(n * NG + (l >> 3)) * 2 + 0] = m;
    stats1[(n * NG + (l >> 3)) * 2 + 1] = rsqrtf(v + 1e-5f);
  }
}

// ---------------- Kernel P: weight prep (w2->bf16 [k][co][ci], w1->f16 pad)
__global__ __launch_bounds__(256) void k_prep(
    const float* __restrict__ w2, const float* __restrict__ w1,
    unsigned short* __restrict__ w2tb, _Float16* __restrict__ w1h) {
  int idx = blockIdx.x * 256 + threadIdx.x;
  if (idx < 7 * 64 * 64) {
    int kk = idx >> 12;
    int r = idx & 4095;
    int co = r >> 6, ci = r & 63;
    w2tb[idx] = (unsigned short)f2bf(w2[(co * 64 + ci) * 7 + kk]);
  } else {
    int r = idx - 28672;
    if (r < 64 * 32) {
      int ci = r >> 5, k = r & 31;
      w1h[r] = (k < 9) ? (_Float16)w1[ci * 9 + k] : (_Float16)0.f;
    }
  }
}

// ---------------- Kernel B: conv1(MFMA f16)+GN1+gelu -> conv2(MFMA bf16) --
// block = (n, 128-t2 tile). MODE 0: GN2 stats. MODE 1: GN2+gelu+time-sum.
template <int MODE>
__global__ __launch_bounds__(256, 3) void k_pass(
    const float* __restrict__ x, const _Float16* __restrict__ w1h,
    const float* __restrict__ g1, const float* __restrict__ b1,
    const float* __restrict__ stats1, const unsigned short* __restrict__ w2tb,
    const float* __restrict__ g2, const float* __restrict__ b2,
    float* __restrict__ stats2, float* __restrict__ hbar) {
  constexpr int ROWS = 272, HS = 72;
  __shared__ unsigned short h1s[ROWS * HS];   // 39168 B, bf16 bits [t'][ci]
  __shared__ _Float16 xh[584];
  __shared__ float scs[TW], bss[TW];

  const int tid = threadIdx.x;
  const int n = blockIdx.x >> 3;
  const int t0 = (blockIdx.x & 7) << 7;       // *128

  const float* xr = x + (size_t)n * TIN;
  for (int i = tid; i < 584; i += 256) {
    int xi = 4 * t0 - 10 + i;
    xh[i] = (xi >= 0 && xi < TIN) ? (_Float16)xr[xi] : (_Float16)0.f;
  }
  if (tid < TW) {
    int ci = tid, g = ci >> 3;
    float m = stats1[(n * NG + g) * 2 + 0];
    float is = stats1[(n * NG + g) * 2 + 1];
    float s = is * g1[ci];
    scs[ci] = s;
    bss[ci] = b1[ci] - m * s;
  }
  __syncthreads();

  const int lane = tid & 63;
  const int wv = tid >> 6;
  const int m = lane & 15;
  const int q = lane >> 4;

  // ---- phase A: conv1 via f16 MFMA (K=32, zero-padded), GN1+gelu, pack ----
  f16x8 w1f[4];
#pragma unroll
  for (int nt = 0; nt < 4; nt++)
    w1f[nt] = *(const f16x8*)&w1h[(nt * 16 + m) * 32 + 8 * q];
  float sc4[4], bs4[4];
#pragma unroll
  for (int nt = 0; nt < 4; nt++) {
    sc4[nt] = scs[nt * 16 + m];
    bs4[nt] = bss[nt * 16 + m];
  }
  for (int mt = wv; mt < 17; mt += 4) {
    int r0 = mt * 16;
    int xi0 = 2 * (r0 + m) + 8 * q;
    uint4 uu;
    uu.x = *(const unsigned*)&xh[xi0 + 0];
    uu.y = *(const unsigned*)&xh[xi0 + 2];
    uu.z = *(const unsigned*)&xh[xi0 + 4];
    uu.w = *(const unsigned*)&xh[xi0 + 6];
    f16x8 af = __builtin_bit_cast(f16x8, uu);
    int rowb = r0 + 4 * q;
    int tpb = 2 * t0 - 3 + rowb;
#pragma unroll
    for (int nt = 0; nt < 4; nt++) {
      f32x4 d = __builtin_amdgcn_mfma_f32_16x16x32_f16(
          af, w1f[nt], (f32x4){0.f, 0.f, 0.f, 0.f}, 0, 0, 0);
#pragma unroll
      for (int r = 0; r < 4; r++) {
        int tp = tpb + r;
        float v = 0.f;
        if (tp >= 0 && tp < T1)
          v = gelu_fast(fmaf(d[r], sc4[nt], bs4[nt]));
        h1s[(rowb + r) * HS + nt * 16 + m] = (unsigned short)f2bf(v);
      }
    }
  }
  __syncthreads();

  // ---- phase B: conv2 bf16 MFMA. wave = (tpart 64t) x (npart 32co) ----
  const int tpart = wv & 1;
  const int npart = wv >> 1;
  f32x4 acc[4][2];
#pragma unroll
  for (int mt = 0; mt < 4; mt++)
#pragma unroll
    for (int nt = 0; nt < 2; nt++) acc[mt][nt] = (f32x4){0.f, 0.f, 0.f, 0.f};

  for (int kk = 0; kk < 7; kk++) {
    bf16x8 afr[4][2], bfr[2][2];
#pragma unroll
    for (int mt = 0; mt < 4; mt++) {
      int tl = 2 * (tpart * 64 + mt * 16 + m) + kk;
#pragma unroll
      for (int ks = 0; ks < 2; ks++)
        afr[mt][ks] = *(const bf16x8*)&h1s[tl * HS + 32 * ks + 8 * q];
    }
#pragma unroll
    for (int nt = 0; nt < 2; nt++) {
      int co = npart * 32 + nt * 16 + m;
#pragma unroll
      for (int ks = 0; ks < 2; ks++)
        bfr[nt][ks] = *(const bf16x8*)&w2tb[(kk * 64 + co) * 64 + 32 * ks + 8 * q];
    }
#pragma unroll
    for (int ks = 0; ks < 2; ks++)
#pragma unroll
      for (int mt = 0; mt < 4; mt++)
#pragma unroll
        for (int nt = 0; nt < 2; nt++)
          acc[mt][nt] = __builtin_amdgcn_mfma_f32_16x16x32_bf16(
              afr[mt][ks], bfr[nt][ks], acc[mt][nt], 0, 0, 0);
  }

  if constexpr (MODE == 0) {
    float sum[2] = {0.f, 0.f}, ssq[2] = {0.f, 0.f};
#pragma unroll
    for (int mt = 0; mt < 4; mt++)
#pragma unroll
      for (int nt = 0; nt < 2; nt++)
#pragma unroll
        for (int r = 0; r < 4; r++) {
          float v = acc[mt][nt][r];
          sum[nt] += v; ssq[nt] += v * v;
        }
#pragma unroll
    for (int nt = 0; nt < 2; nt++) {
      sum[nt] += __shfl_xor(sum[nt], 1, 64);  ssq[nt] += __shfl_xor(ssq[nt], 1, 64);
      sum[nt] += __shfl_xor(sum[nt], 2, 64);  ssq[nt] += __shfl_xor(ssq[nt], 2, 64);
      sum[nt] += __shfl_xor(sum[nt], 4, 64);  ssq[nt] += __shfl_xor(ssq[nt], 4, 64);
      sum[nt] += __shfl_xor(sum[nt], 16, 64); ssq[nt] += __shfl_xor(ssq[nt], 16, 64);
      sum[nt] += __shfl_xor(sum[nt], 32, 64); ssq[nt] += __shfl_xor(ssq[nt], 32, 64);
    }
    if (lane == 0 || lane == 8) {
      int gb = (lane >> 3) & 1;
#pragma unroll
      for (int nt = 0; nt < 2; nt++) {
        int g = npart * 4 + nt * 2 + gb;
        atomicAdd(&stats2[(n * NG + g) * 2 + 0], sum[nt]);
        atomicAdd(&stats2[(n * NG + g) * 2 + 1], ssq[nt]);
      }
    }
  } else {
    float sca[2], sh[2], p[2] = {0.f, 0.f};
#pragma unroll
    for (int nt = 0; nt < 2; nt++) {
      int co = npart * 32 + nt * 16 + m;
      int g = co >> 3;
      float mn = stats2[(n * NG + g) * 2 + 0] * (1.f / 8192.f);
      float e2 = stats2[(n * NG + g) * 2 + 1] * (1.f / 8192.f);
      float is = rsqrtf(e2 - mn * mn + 1e-5f);
      sca[nt] = is * g2[co];
      sh[nt] = b2[co] - mn * sca[nt];
    }
#pragma unroll
    for (int mt = 0; mt < 4; mt++)
#pragma unroll
      for (int nt = 0; nt < 2; nt++)
#pragma unroll
        for (int r = 0; r < 4; r++)
          p[nt] += gelu_fast(fmaf(acc[mt][nt][r], sca[nt], sh[nt]));
#pragma unroll
    for (int nt = 0; nt < 2; nt++) {
      p[nt] += __shfl_xor(p[nt], 16, 64);
      p[nt] += __shfl_xor(p[nt], 32, 64);
    }
    if (q == 0) {
#pragma unroll
      for (int nt = 0; nt < 2; nt++)
        atomicAdd(&hbar[n * TW + npart * 32 + nt * 16 + m], p[nt]);
    }
  }
}

// ---------------- Kernel D: proj + GCN layers + LN + node mean ------------
__global__ __launch_bounds__(256) void k_head(
    const float* __restrict__ hbar,
    const float* __restrict__ pw, const float* __restrict__ pb,
    const float* __restrict__ A,
    const float* __restrict__ l1w, const float* __restrict__ l1g, const float* __restrict__ l1b,
    const float* __restrict__ l2w, const float* __restrict__ l2g, const float* __restrict__ l2b,
    const float* __restrict__ og, const float* __restrict__ ob,
    float* __restrict__ out) {
  int b = blockIdx.x;
  __shared__ float h4[4][TW];
  __shared__ float H[4][DD];
  __shared__ float Hm[4][DD];
  __shared__ float Xs[4][DD];
  __shared__ float At[16], Ah[16], dinv[4];
  {
    int i = threadIdx.x;
    int c = i >> 6, k = i & 63;
    h4[c][k] = hbar[(b * 4 + c) * TW + k] * (1.f / 1024.f);
  }
  if (threadIdx.x < 16)
    At[threadIdx.x] = A[threadIdx.x] + ((threadIdx.x % 5) == 0 ? 1.f : 0.f);
  __syncthreads();
  if (threadIdx.x < 4) {
    float dg = At[threadIdx.x * 4] + At[threadIdx.x * 4 + 1] +
               At[threadIdx.x * 4 + 2] + At[threadIdx.x * 4 + 3];
    dinv[threadIdx.x] = rsqrtf(dg + 1e-6f);
  }
  for (int idx = threadIdx.x; idx < 512; idx += 256) {
    int c = idx >> 7, d = idx & 127;
    float acc = pb[d];
    const float* wrow = pw + d * TW;
#pragma unroll 8
    for (int k = 0; k < TW; k++) acc += h4[c][k] * wrow[k];
    H[c][d] = acc;
  }
  __syncthreads();
  if (threadIdx.x < 16)
    Ah[threadIdx.x] = dinv[threadIdx.x >> 2] * At[threadIdx.x] * dinv[threadIdx.x & 3];
  __syncthreads();
  for (int L = 0; L < 2; L++) {
    const float* lw = L ? l2w : l1w;
    const float* lg = L ? l2g : l1g;
    const float* lb = L ? l2b : l1b;
    for (int idx = threadIdx.x; idx < 512; idx += 256) {
      int nn = idx >> 7, d = idx & 127;
      Hm[nn][d] = Ah[nn * 4 + 0] * H[0][d] + Ah[nn * 4 + 1] * H[1][d] +
                  Ah[nn * 4 + 2] * H[2][d] + Ah[nn * 4 + 3] * H[3][d];
    }
    __syncthreads();
    for (int idx = threadIdx.x; idx < 512; idx += 256) {
      int nn = idx >> 7, d = idx & 127;
      float acc = 0.f;
      const float* wrow = lw + d * DD;
#pragma unroll 8
      for (int k = 0; k < DD; k++) acc += Hm[nn][k] * wrow[k];
      Xs[nn][d] = acc;
    }
    __syncthreads();
    {
      int w = threadIdx.x >> 6, lane = threadIdx.x & 63;
      float v0 = Xs[w][lane], v1 = Xs[w][lane + 64];
      float s = v0 + v1, qq = v0 * v0 + v1 * v1;
#pragma unroll
      for (int off = 1; off < 64; off <<= 1) {
        s += __shfl_xor(s, off, 64);
        qq += __shfl_xor(qq, off, 64);
      }
      float mm = s * (1.f / 128.f);
      float istd = rsqrtf(qq * (1.f / 128.f) - mm * mm + 1e-5f);
      H[w][lane]      = gelu_fast((v0 - mm) * istd * lg[lane] + lb[lane]);
      H[w][lane + 64] = gelu_fast((v1 - mm) * istd * lg[lane + 64] + lb[lane + 64]);
    }
    __syncthreads();
  }
  {
    int w = threadIdx.x >> 6, lane = threadIdx.x & 63;
    float v0 = H[w][lane], v1 = H[w][lane + 64];
    float s = v0 + v1, qq = v0 * v0 + v1 * v1;
#pragma unroll
    for (int off = 1; off < 64; off <<= 1) {
      s += __shfl_xor(s, off, 64);
      qq += __shfl_xor(qq, off, 64);
    }
    float mm = s * (1.f / 128.f);
    float istd = rsqrtf(qq * (1.f / 128.f) - mm * mm + 1e-5f);
    Xs[w][lane]      = (v0 - mm) * istd * og[lane] + ob[lane];
    Xs[w][lane + 64] = (v1 - mm) * istd * og[lane + 64] + ob[lane + 64];
  }
  __syncthreads();
  if (threadIdx.x < DD) {
    int d = threadIdx.x;
    out[b * DD + d] = 0.25f * (Xs[0][d] + Xs[1][d] + Xs[2][d] + Xs[3][d]);
  }
}

extern "C" void kernel_launch(void* const* d_in, const int* in_sizes, int n_in,
                              void* d_out, int out_size, void* d_ws, size_t ws_size,
                              hipStream_t stream) {
  (void)in_sizes; (void)n_in; (void)out_size; (void)ws_size;
  const float* x       = (const float*)d_in[0];
  const float* conv1_w = (const float*)d_in[1];
  const float* gn1_g   = (const float*)d_in[2];
  const float* gn1_b   = (const float*)d_in[3];
  const float* conv2_w = (const float*)d_in[4];
  const float* gn2_g   = (const float*)d_in[5];
  const float* gn2_b   = (const float*)d_in[6];
  const float* proj_w  = (const float*)d_in[7];
  const float* proj_b  = (const float*)d_in[8];
  const float* A       = (const float*)d_in[9];
  const float* lin1_w  = (const float*)d_in[10];
  const float* ln1_g   = (const float*)d_in[11];
  const float* ln1_b   = (const float*)d_in[12];
  const float* lin2_w  = (const float*)d_in[13];
  const float* ln2_g   = (const float*)d_in[14];
  const float* ln2_b   = (const float*)d_in[15];
  const float* on_g    = (const float*)d_in[16];
  const float* on_b    = (const float*)d_in[17];
  float* out = (float*)d_out;

  float* wsf = (float*)d_ws;
  float* stats2 = wsf;                              // 16384 f
  float* hbar   = wsf + 16384;                      // 65536 f
  float* stats1 = wsf + 81920;                      // 16384 f
  unsigned short* w2tb = (unsigned short*)(wsf + 98304);   // 28672 us
  _Float16* w1h = (_Float16*)(wsf + 112640);        // 2048 f16

  hipMemsetAsync(stats2, 0, (16384 + 65536) * sizeof(float), stream);
  k_prep<<<120, 256, 0, stream>>>(conv2_w, conv1_w, w2tb, w1h);
  k_stats1<<<NS, 64, 0, stream>>>(x, conv1_w, stats1);
  k_pass<0><<<NS * 8, 256, 0, stream>>>(x, w1h, gn1_g, gn1_b, stats1, w2tb,
                                        gn2_g, gn2_b, stats2, hbar);
  k_pass<1><<<NS * 8, 256, 0, stream>>>(x, w1h, gn1_g, gn1_b, stats1, w2tb,
                                        gn2_g, gn2_b, stats2, hbar);
  k_head<<<256, 256, 0, stream>>>(hbar, proj_w, proj_b, A,
                                  lin1_w, ln1_g, ln1_b,
                                  lin2_w, ln2_g, ln2_b,
                                  on_g, on_b, out);
}

// Round 5
// 331.796 us; speedup vs baseline: 51.7060x; 1.3893x over previous
//
#include <hip/hip_runtime.h>
#include <hip/hip_fp16.h>
#include <math.h>

#define NS   1024
#define TIN  4096
#define T1   2048
#define T2   1024
#define TW   64
#define NG   8
#define DD   128

typedef __attribute__((ext_vector_type(8))) _Float16 f16x8;
typedef __attribute__((ext_vector_type(4))) float    f32x4;

// tanh-form gelu, exp folded to exp2 (|dev from exact| ~3e-4)
__device__ __forceinline__ float gelu_fast(float x) {
  float t = x * x;
  float p = fmaf(0.044715f, t, 1.0f);
  float u = 2.3022038f * x * p;              // 2*sqrt(2/pi)*log2(e)
  float e = exp2f(u);
  float r = __builtin_amdgcn_rcpf(e + 1.0f);
  return fmaf(-x, r, x);                      // x * e/(e+1)
}

// ---------------- Kernel A: conv1 stats per n via 9x9 Gram matrix ---------
__global__ __launch_bounds__(64) void k_stats1(
    const float* __restrict__ x, const float* __restrict__ w1,
    float* __restrict__ stats1) {
  int n = blockIdx.x;
  __shared__ float xw[4112];
  const float* xr = x + (size_t)n * TIN;
  for (int i = threadIdx.x; i < 4112; i += 64) {
    int xi = i - 4;
    xw[i] = (xi >= 0 && xi < TIN) ? xr[xi] : 0.f;
  }
  __syncthreads();
  float C[45], S[9];
#pragma unroll
  for (int c = 0; c < 45; c++) C[c] = 0.f;
#pragma unroll
  for (int i = 0; i < 9; i++) S[i] = 0.f;
  int l = threadIdx.x;
  for (int j = 0; j < 32; j++) {
    int t = l + 64 * j;
    float w[9];
#pragma unroll
    for (int i = 0; i < 9; i++) w[i] = xw[2 * t + i];
#pragma unroll
    for (int i = 0; i < 9; i++) S[i] += w[i];
    int c = 0;
#pragma unroll
    for (int i = 0; i < 9; i++)
#pragma unroll
      for (int jj = i; jj < 9; jj++) { C[c] = fmaf(w[i], w[jj], C[c]); c++; }
  }
#pragma unroll
  for (int off = 1; off < 64; off <<= 1) {
#pragma unroll
    for (int i = 0; i < 9; i++) S[i] += __shfl_xor(S[i], off, 64);
#pragma unroll
    for (int c = 0; c < 45; c++) C[c] += __shfl_xor(C[c], off, 64);
  }
  float wv[9];
#pragma unroll
  for (int i = 0; i < 9; i++) wv[i] = w1[l * 9 + i];
  float sm = 0.f, sq = 0.f;
  {
    int c = 0;
#pragma unroll
    for (int i = 0; i < 9; i++) {
      sm = fmaf(wv[i], S[i], sm);
#pragma unroll
      for (int jj = i; jj < 9; jj++) {
        float f = (jj == i) ? wv[i] * wv[jj] : 2.f * wv[i] * wv[jj];
        sq = fmaf(f, C[c], sq); c++;
      }
    }
  }
#pragma unroll
  for (int off = 1; off < 8; off <<= 1) {
    sm += __shfl_xor(sm, off, 64);
    sq += __shfl_xor(sq, off, 64);
  }
  if ((l & 7) == 0) {
    float m = sm * (1.f / 16384.f);
    float v = sq * (1.f / 16384.f) - m * m;
    stats1[(n * NG + (l >> 3)) * 2 + 0] = m;
    stats1[(n * NG + (l >> 3)) * 2 + 1] = rsqrtf(v + 1e-5f);
  }
}

// ---------------- Kernel P: weight prep -> f16 ----------------------------
__global__ __launch_bounds__(256) void k_prep(
    const float* __restrict__ w2, const float* __restrict__ w1,
    _Float16* __restrict__ w2tf, _Float16* __restrict__ w1h) {
  int idx = blockIdx.x * 256 + threadIdx.x;
  if (idx < 7 * 64 * 64) {
    int kk = idx >> 12;
    int r = idx & 4095;
    int co = r >> 6, ci = r & 63;
    w2tf[idx] = (_Float16)w2[(co * 64 + ci) * 7 + kk];
  } else {
    int r = idx - 28672;
    if (r < 64 * 32) {
      int ci = r >> 5, k = r & 31;
      w1h[r] = (k < 9) ? (_Float16)w1[ci * 9 + k] : (_Float16)0.f;
    }
  }
}

// ---------------- Kernel B: conv1(MFMA)+GN1+gelu -> conv2(MFMA) -> y2 -----
// block = (n, 64-t2 tile). 256 thr = 4 waves; wave = 64 t x 16 co.
__global__ __launch_bounds__(256, 6) void k_conv(
    const float* __restrict__ x, const _Float16* __restrict__ w1h,
    const float* __restrict__ g1, const float* __restrict__ b1,
    const float* __restrict__ stats1, const _Float16* __restrict__ w2tf,
    __half* __restrict__ y2, float* __restrict__ stats2) {
  constexpr int ROWS = 144, HS = 72;
  __shared__ _Float16 h1s[ROWS * HS];         // 20736 B; reused as tr[64][72]
  __shared__ _Float16 xh[320];
  __shared__ float scs[TW], bss[TW];

  const int tid = threadIdx.x;
  const int n = blockIdx.x >> 4;
  const int tile = blockIdx.x & 15;
  const int t0 = tile << 6;
  const bool chk = (tile == 0) || (tile == 15);

  const float* xr = x + (size_t)n * TIN;
  for (int i = tid; i < 320; i += 256) {
    int xi = 4 * t0 - 10 + i;
    xh[i] = (i < 278 && xi >= 0 && xi < TIN) ? (_Float16)xr[xi] : (_Float16)0.f;
  }
  if (tid < TW) {
    int ci = tid, g = ci >> 3;
    float m = stats1[(n * NG + g) * 2 + 0];
    float is = stats1[(n * NG + g) * 2 + 1];
    float s = is * g1[ci];
    scs[ci] = s;
    bss[ci] = b1[ci] - m * s;
  }
  __syncthreads();

  const int lane = tid & 63;
  const int wv = tid >> 6;
  const int m = lane & 15;
  const int q = lane >> 4;

  // ---- phase A: conv1 via f16 MFMA (K padded 9->32), GN1+gelu, store f16 --
  {
    f16x8 w1f[4];
#pragma unroll
    for (int nt = 0; nt < 4; nt++)
      w1f[nt] = *(const f16x8*)&w1h[(nt * 16 + m) * 32 + 8 * q];
    float sc4[4], bs4[4];
#pragma unroll
    for (int nt = 0; nt < 4; nt++) {
      sc4[nt] = scs[nt * 16 + m];
      bs4[nt] = bss[nt * 16 + m];
    }
    for (int mt = wv; mt < 9; mt += 4) {
      int r0 = mt * 16;
      int xi0 = 2 * (r0 + m) + 8 * q;
      uint4 uu;
      uu.x = *(const unsigned*)&xh[xi0 + 0];
      uu.y = *(const unsigned*)&xh[xi0 + 2];
      uu.z = *(const unsigned*)&xh[xi0 + 4];
      uu.w = *(const unsigned*)&xh[xi0 + 6];
      f16x8 af = __builtin_bit_cast(f16x8, uu);
      int rowb = r0 + 4 * q;
#pragma unroll
      for (int nt = 0; nt < 4; nt++) {
        f32x4 d = __builtin_amdgcn_mfma_f32_16x16x32_f16(
            af, w1f[nt], (f32x4){0.f, 0.f, 0.f, 0.f}, 0, 0, 0);
#pragma unroll
        for (int r = 0; r < 4; r++) {
          float v = gelu_fast(fmaf(d[r], sc4[nt], bs4[nt]));
          if (chk) {
            int tp = 2 * t0 - 3 + rowb + r;
            if ((unsigned)tp >= (unsigned)T1) v = 0.f;
          }
          h1s[(rowb + r) * HS + nt * 16 + m] = (_Float16)v;
        }
      }
    }
  }
  __syncthreads();

  // ---- phase B: conv2 f16 MFMA. wave = all 64 t x 16-co slice ----
  const int co0 = wv * 16 + m;
  f32x4 acc[4];
#pragma unroll
  for (int mt = 0; mt < 4; mt++) acc[mt] = (f32x4){0.f, 0.f, 0.f, 0.f};

  for (int kk = 0; kk < 7; kk++) {
    f16x8 bfr[2];
#pragma unroll
    for (int ks = 0; ks < 2; ks++)
      bfr[ks] = *(const f16x8*)&w2tf[(kk * 64 + co0) * 64 + 32 * ks + 8 * q];
#pragma unroll
    for (int mt = 0; mt < 4; mt++) {
      int tl = 2 * (mt * 16 + m) + kk;
      f16x8 a0 = *(const f16x8*)&h1s[tl * HS + 8 * q];
      f16x8 a1 = *(const f16x8*)&h1s[tl * HS + 32 + 8 * q];
      acc[mt] = __builtin_amdgcn_mfma_f32_16x16x32_f16(a0, bfr[0], acc[mt], 0, 0, 0);
      acc[mt] = __builtin_amdgcn_mfma_f32_16x16x32_f16(a1, bfr[1], acc[mt], 0, 0, 0);
    }
  }

  // ---- epilogue: GN2 stats + transpose via LDS + coalesced y2 store ----
  float sum = 0.f, ssq = 0.f;
#pragma unroll
  for (int mt = 0; mt < 4; mt++)
#pragma unroll
    for (int r = 0; r < 4; r++) {
      float v = acc[mt][r];
      sum += v; ssq += v * v;
    }
  sum += __shfl_xor(sum, 1, 64);  ssq += __shfl_xor(ssq, 1, 64);
  sum += __shfl_xor(sum, 2, 64);  ssq += __shfl_xor(ssq, 2, 64);
  sum += __shfl_xor(sum, 4, 64);  ssq += __shfl_xor(ssq, 4, 64);
  sum += __shfl_xor(sum, 16, 64); ssq += __shfl_xor(ssq, 16, 64);
  sum += __shfl_xor(sum, 32, 64); ssq += __shfl_xor(ssq, 32, 64);
  if (lane == 0 || lane == 8) {
    int g = 2 * wv + (lane >> 3);
    atomicAdd(&stats2[(n * NG + g) * 2 + 0], sum);
    atomicAdd(&stats2[(n * NG + g) * 2 + 1], ssq);
  }

  __syncthreads();                      // all h1s reads done; reuse as tr
  __half* tr = (__half*)h1s;            // [64 t][72] fp16
#pragma unroll
  for (int mt = 0; mt < 4; mt++)
#pragma unroll
    for (int r = 0; r < 4; r++) {
      int t = mt * 16 + q * 4 + r;
      tr[t * HS + co0] = __float2half(acc[mt][r]);
    }
  __syncthreads();
  for (int idx = tid; idx < 512; idx += 256) {
    int t = idx >> 3, c8 = (idx & 7) * 8;
    float4 v = *(float4*)&tr[t * HS + c8];
    *(float4*)&y2[((size_t)(n * 1024) + t0 + t) * 64 + c8] = v;
  }
}

// ---------------- Kernel C: GN2 + gelu + time-sum -> hbar -----------------
__global__ __launch_bounds__(256) void k_gn2mean(
    const __half* __restrict__ y2, const float* __restrict__ stats2,
    const float* __restrict__ g2, const float* __restrict__ b2,
    float* __restrict__ hbar) {
  int n = blockIdx.x;
  int coct = threadIdx.x & 7;           // co-oct: co 8*coct..+7 == GN2 group
  int tsl = threadIdx.x >> 3;           // 32 t-slices
  int co0 = coct * 8;
  float mn = stats2[(n * NG + coct) * 2 + 0] * (1.f / 8192.f);
  float e2 = stats2[(n * NG + coct) * 2 + 1] * (1.f / 8192.f);
  float istd = rsqrtf(e2 - mn * mn + 1e-5f);
  float sca[8], sh[8];
#pragma unroll
  for (int j = 0; j < 8; j++) {
    sca[j] = istd * g2[co0 + j];
    sh[j] = b2[co0 + j] - mn * sca[j];
  }
  const __half* base = y2 + (size_t)n * 65536;
  float a[8];
#pragma unroll
  for (int j = 0; j < 8; j++) a[j] = 0.f;
  for (int i = 0; i < 32; i++) {
    int t = tsl + 32 * i;
    float4 raw = *(const float4*)&base[t * 64 + co0];
    __half2 hh[4];
    *(float4*)hh = raw;
#pragma unroll
    for (int p = 0; p < 4; p++) {
      float2 f = __half22float2(hh[p]);
      a[2 * p]     += gelu_fast(fmaf(f.x, sca[2 * p], sh[2 * p]));
      a[2 * p + 1] += gelu_fast(fmaf(f.y, sca[2 * p + 1], sh[2 * p + 1]));
    }
  }
  __shared__ float red[32][64];
  *(float4*)&red[tsl][co0] = *(float4*)&a[0];
  *(float4*)&red[tsl][co0 + 4] = *(float4*)&a[4];
  __syncthreads();
  if (threadIdx.x < 64) {
    float s = 0.f;
#pragma unroll 8
    for (int r = 0; r < 32; r++) s += red[r][threadIdx.x];
    hbar[n * 64 + threadIdx.x] = s;     // SUM over 1024; k_head scales
  }
}

// ---------------- Kernel D: proj + GCN layers + LN + node mean ------------
__global__ __launch_bounds__(256) void k_head(
    const float* __restrict__ hbar,
    const float* __restrict__ pw, const float* __restrict__ pb,
    const float* __restrict__ A,
    const float* __restrict__ l1w, const float* __restrict__ l1g, const float* __restrict__ l1b,
    const float* __restrict__ l2w, const float* __restrict__ l2g, const float* __restrict__ l2b,
    const float* __restrict__ og, const float* __restrict__ ob,
    float* __restrict__ out) {
  int b = blockIdx.x;
  __shared__ float h4[4][TW];
  __shared__ float H[4][DD];
  __shared__ float Hm[4][DD];
  __shared__ float Xs[4][DD];
  __shared__ float At[16], Ah[16], dinv[4];
  {
    int i = threadIdx.x;
    int c = i >> 6, k = i & 63;
    h4[c][k] = hbar[(b * 4 + c) * TW + k] * (1.f / 1024.f);
  }
  if (threadIdx.x < 16)
    At[threadIdx.x] = A[threadIdx.x] + ((threadIdx.x % 5) == 0 ? 1.f : 0.f);
  __syncthreads();
  if (threadIdx.x < 4) {
    float dg = At[threadIdx.x * 4] + At[threadIdx.x * 4 + 1] +
               At[threadIdx.x * 4 + 2] + At[threadIdx.x * 4 + 3];
    dinv[threadIdx.x] = rsqrtf(dg + 1e-6f);
  }
  for (int idx = threadIdx.x; idx < 512; idx += 256) {
    int c = idx >> 7, d = idx & 127;
    float acc = pb[d];
    const float* wrow = pw + d * TW;
#pragma unroll 8
    for (int k = 0; k < TW; k++) acc += h4[c][k] * wrow[k];
    H[c][d] = acc;
  }
  __syncthreads();
  if (threadIdx.x < 16)
    Ah[threadIdx.x] = dinv[threadIdx.x >> 2] * At[threadIdx.x] * dinv[threadIdx.x & 3];
  __syncthreads();
  for (int L = 0; L < 2; L++) {
    const float* lw = L ? l2w : l1w;
    const float* lg = L ? l2g : l1g;
    const float* lb = L ? l2b : l1b;
    for (int idx = threadIdx.x; idx < 512; idx += 256) {
      int nn = idx >> 7, d = idx & 127;
      Hm[nn][d] = Ah[nn * 4 + 0] * H[0][d] + Ah[nn * 4 + 1] * H[1][d] +
                  Ah[nn * 4 + 2] * H[2][d] + Ah[nn * 4 + 3] * H[3][d];
    }
    __syncthreads();
    for (int idx = threadIdx.x; idx < 512; idx += 256) {
      int nn = idx >> 7, d = idx & 127;
      float acc = 0.f;
      const float* wrow = lw + d * DD;
#pragma unroll 8
      for (int k = 0; k < DD; k++) acc += Hm[nn][k] * wrow[k];
      Xs[nn][d] = acc;
    }
    __syncthreads();
    {
      int w = threadIdx.x >> 6, lane = threadIdx.x & 63;
      float v0 = Xs[w][lane], v1 = Xs[w][lane + 64];
      float s = v0 + v1, qq = v0 * v0 + v1 * v1;
#pragma unroll
      for (int off = 1; off < 64; off <<= 1) {
        s += __shfl_xor(s, off, 64);
        qq += __shfl_xor(qq, off, 64);
      }
      float mm = s * (1.f / 128.f);
      float istd = rsqrtf(qq * (1.f / 128.f) - mm * mm + 1e-5f);
      H[w][lane]      = gelu_fast((v0 - mm) * istd * lg[lane] + lb[lane]);
      H[w][lane + 64] = gelu_fast((v1 - mm) * istd * lg[lane + 64] + lb[lane + 64]);
    }
    __syncthreads();
  }
  {
    int w = threadIdx.x >> 6, lane = threadIdx.x & 63;
    float v0 = H[w][lane], v1 = H[w][lane + 64];
    float s = v0 + v1, qq = v0 * v0 + v1 * v1;
#pragma unroll
    for (int off = 1; off < 64; off <<= 1) {
      s += __shfl_xor(s, off, 64);
      qq += __shfl_xor(qq, off, 64);
    }
    float mm = s * (1.f / 128.f);
    float istd = rsqrtf(qq * (1.f / 128.f) - mm * mm + 1e-5f);
    Xs[w][lane]      = (v0 - mm) * istd * og[lane] + ob[lane];
    Xs[w][lane + 64] = (v1 - mm) * istd * og[lane + 64] + ob[lane + 64];
  }
  __syncthreads();
  if (threadIdx.x < DD) {
    int d = threadIdx.x;
    out[b * DD + d] = 0.25f * (Xs[0][d] + Xs[1][d] + Xs[2][d] + Xs[3][d]);
  }
}

extern "C" void kernel_launch(void* const* d_in, const int* in_sizes, int n_in,
                              void* d_out, int out_size, void* d_ws, size_t ws_size,
                              hipStream_t stream) {
  (void)in_sizes; (void)n_in; (void)out_size; (void)ws_size;
  const float* x       = (const float*)d_in[0];
  const float* conv1_w = (const float*)d_in[1];
  const float* gn1_g   = (const float*)d_in[2];
  const float* gn1_b   = (const float*)d_in[3];
  const float* conv2_w = (const float*)d_in[4];
  const float* gn2_g   = (const float*)d_in[5];
  const float* gn2_b   = (const float*)d_in[6];
  const float* proj_w  = (const float*)d_in[7];
  const float* proj_b  = (const float*)d_in[8];
  const float* A       = (const float*)d_in[9];
  const float* lin1_w  = (const float*)d_in[10];
  const float* ln1_g   = (const float*)d_in[11];
  const float* ln1_b   = (const float*)d_in[12];
  const float* lin2_w  = (const float*)d_in[13];
  const float* ln2_g   = (const float*)d_in[14];
  const float* ln2_b   = (const float*)d_in[15];
  const float* on_g    = (const float*)d_in[16];
  const float* on_b    = (const float*)d_in[17];
  float* out = (float*)d_out;

  float* wsf = (float*)d_ws;
  float* stats2 = wsf;                              // 16384 f
  float* stats1 = wsf + 16384;                      // 16384 f
  float* hbar   = wsf + 32768;                      // 65536 f
  _Float16* w2tf = (_Float16*)(wsf + 98304);        // 28672 f16
  _Float16* w1h  = (_Float16*)(wsf + 112640);       // 2048 f16
  __half* y2h    = (__half*)(wsf + 113664);         // 67108864 f16 (128 MB)

  hipMemsetAsync(stats2, 0, 16384 * sizeof(float), stream);
  k_prep<<<120, 256, 0, stream>>>(conv2_w, conv1_w, w2tf, w1h);
  k_stats1<<<NS, 64, 0, stream>>>(x, conv1_w, stats1);
  k_conv<<<NS * 16, 256, 0, stream>>>(x, w1h, gn1_g, gn1_b, stats1, w2tf,
                                      y2h, stats2);
  k_gn2mean<<<NS, 256, 0, stream>>>(y2h, stats2, gn2_g, gn2_b, hbar);
  k_head<<<256, 256, 0, stream>>>(hbar, proj_w, proj_b, A,
                                  lin1_w, ln1_g, ln1_b,
                                  lin2_w, ln2_g, ln2_b,
                                  on_g, on_b, out);
}